// Round 5
// baseline (963.694 us; speedup 1.0000x reference)
//
#include <hip/hip_runtime.h>
#include <hip/hip_fp16.h>
#include <hip/hip_cooperative_groups.h>

namespace cg = cooperative_groups;

// MPNN flocking, cooperative single-kernel (with multi-kernel fallback).
// R4 failed: coop launch never ran (unchecked error; GRID=1024 demanded exactly
// 4 blocks/CU). R5: GRID=512 (2 blocks/CU guaranteed by launch_bounds(256,2)),
// launch return code checked -> proven fallback path if coop unavailable.
// Correctness under XCD non-coherence: stats written with memory-side f64
// atomics, read with AGENT-scope atomic loads (bypass stale L2); per-XCD
// aggregate copies written with WORKGROUP-scope (L2-local) atomics by same-XCD
// blocks only; merged into final by same-XCD blocks via far atomics; final
// aggregate read with AGENT-scope atomic loads.

#define TPB 256
#define CGRID 512
#define EPT 49                    // 512*256*49 = 6,422,528 >= E = 6,400,000
#define AGGR_SCALE 128.0f
#define AGGR_INV (1.0f / 128.0f)

struct alignas(8) half4v { _Float16 v[4]; };

struct Params {
  const int* esrc; const int* edst;
  const float* pos; const float* vel;
  const float* msgW2; const float* msgb2;
  const float* msgg1; const float* msgbe1;
  const float* msgg2; const float* msgbe2;
  const float* updW1; const float* updb1;
  const float* updg1; const float* updbe1;
  const float* updW2; const float* updb2;
  const float* updg2; const float* updbe2;
  const float* predW; const float* predb;
  const half4v* a16; const half4v* b16;
  unsigned long long* aggrF;    // [N]  final packed aggregate
  unsigned long long* copies;   // [8N] per-XCD partials
  double* stats;                // [32]
  unsigned* ctr;                // [8]  per-XCD merge chunk counters
  float2* out;
  int N, E;
  double invE, invN;
};

__device__ __forceinline__ void load_w44(const float* __restrict__ W, float w[4][4]) {
  #pragma unroll
  for (int k = 0; k < 4; ++k)
    #pragma unroll
    for (int j = 0; j < 4; ++j) w[k][j] = W[k * 4 + j];
}

__device__ __forceinline__ void layer2(const float r[4], const float w[4][4],
                                       const float bb[4], float y[4]) {
  #pragma unroll
  for (int j = 0; j < 4; ++j) {
    float t = bb[j];
    t = fmaf(r[0], w[0][j], t); t = fmaf(r[1], w[1][j], t);
    t = fmaf(r[2], w[2][j], t); t = fmaf(r[3], w[3][j], t);
    y[j] = t;
  }
}

__device__ __forceinline__ float4 unpack_aggr(unsigned long long pk) {
  return make_float4((float)(unsigned)(pk & 0xFFFFull) * AGGR_INV,
                     (float)(unsigned)((pk >> 16) & 0xFFFFull) * AGGR_INV,
                     (float)(unsigned)((pk >> 32) & 0xFFFFull) * AGGR_INV,
                     (float)(unsigned)((pk >> 48) & 0xFFFFull) * AGGR_INV);
}

__device__ __forceinline__ unsigned long long pack_msg(const half4v q, const float sc1[4],
                                                       const float sh1[4], const float w2[4][4],
                                                       const float bb2[4], const float sc2[4],
                                                       const float sh2[4]) {
  float r[4], y2[4];
  #pragma unroll
  for (int j = 0; j < 4; ++j) r[j] = fmaxf(0.f, fmaf((float)q.v[j], sc1[j], sh1[j]));
  layer2(r, w2, bb2, y2);
  unsigned long long pk = 0ull;
  #pragma unroll
  for (int j = 0; j < 4; ++j) {
    float m = fmaxf(0.f, fmaf(y2[j], sc2[j], sh2[j]));
    unsigned qq = (unsigned)(fmaf(m, AGGR_SCALE, 0.5f));
    qq = qq > 0xFFFFu ? 0xFFFFu : qq;
    pk |= (unsigned long long)qq << (16 * j);
  }
  return pk;
}

__device__ void block_reduce_add8(float v[8], double* __restrict__ dst) {
  __shared__ float redsm[TPB / 64][8];
  __syncthreads();
  #pragma unroll
  for (int k = 0; k < 8; ++k) {
    float x = v[k];
    #pragma unroll
    for (int off = 32; off > 0; off >>= 1) x += __shfl_down(x, off, 64);
    v[k] = x;
  }
  const int lane = threadIdx.x & 63;
  const int wave = threadIdx.x >> 6;
  if (lane == 0) {
    #pragma unroll
    for (int k = 0; k < 8; ++k) redsm[wave][k] = v[k];
  }
  __syncthreads();
  if (threadIdx.x == 0) {
    #pragma unroll
    for (int k = 0; k < 8; ++k) {
      float t = 0.f;
      #pragma unroll
      for (int w = 0; w < TPB / 64; ++w) t += redsm[w][k];
      unsafeAtomicAdd(&dst[k], (double)t);   // memory-side f64 atomic
    }
  }
}

__device__ void finalize_bn_block(double* sg, const float* __restrict__ g,
                                  const float* __restrict__ be, double invCnt,
                                  float sc[4], float sh[4]) {
  __shared__ float bn_sm[8];
  __syncthreads();
  if (threadIdx.x < 4) {
    int j = threadIdx.x;
    double s  = __hip_atomic_load(&sg[j],     __ATOMIC_RELAXED, __HIP_MEMORY_SCOPE_AGENT);
    double s2 = __hip_atomic_load(&sg[4 + j], __ATOMIC_RELAXED, __HIP_MEMORY_SCOPE_AGENT);
    float mean = (float)(s * invCnt);
    float ex2  = (float)(s2 * invCnt);
    float var  = ex2 - mean * mean;
    float scv = g[j] * rsqrtf(var + 1e-5f);
    bn_sm[j] = scv;
    bn_sm[4 + j] = be[j] - mean * scv;
  }
  __syncthreads();
  #pragma unroll
  for (int j = 0; j < 4; ++j) { sc[j] = bn_sm[j]; sh[j] = bn_sm[4 + j]; }
}

// a16[n] = h@W1[0:4] + b1 (dst side);  b16[n] = h@W1[4:8] (src side)
__global__ void node_prep(const float* __restrict__ pos, const float* __restrict__ vel,
                          const float* __restrict__ W1, const float* __restrict__ b1,
                          half4v* __restrict__ a16, half4v* __restrict__ b16, int n) {
  int i = blockIdx.x * blockDim.x + threadIdx.x;
  if (i < n) {
    float2 p = ((const float2*)pos)[i];
    float2 v = ((const float2*)vel)[i];
    half4v ha, hb;
    #pragma unroll
    for (int j = 0; j < 4; ++j) {
      float a = b1[j];
      a = fmaf(p.x, W1[0 * 4 + j], a); a = fmaf(p.y, W1[1 * 4 + j], a);
      a = fmaf(v.x, W1[2 * 4 + j], a); a = fmaf(v.y, W1[3 * 4 + j], a);
      float b = 0.f;
      b = fmaf(p.x, W1[4 * 4 + j], b); b = fmaf(p.y, W1[5 * 4 + j], b);
      b = fmaf(v.x, W1[6 * 4 + j], b); b = fmaf(v.y, W1[7 * 4 + j], b);
      ha.v[j] = (_Float16)a;
      hb.v[j] = (_Float16)b;
    }
    a16[i] = ha;
    b16[i] = hb;
  }
}

// ======================= cooperative mega kernel ==========================
__global__ __launch_bounds__(TPB, 2) void mega(Params p) {
  const int tid = blockIdx.x * TPB + threadIdx.x;
  const int S = CGRID * TPB;
  const int CAP = S * EPT;

  unsigned xcc_id;
  asm("s_getreg_b32 %0, hwreg(HW_REG_XCC_ID)" : "=s"(xcc_id));
  const int xcd = (int)(xcc_id & 7u);
  unsigned long long* __restrict__ myCopy = p.copies + (size_t)xcd * (size_t)p.N;

  cg::grid_group grid = cg::this_grid();

  // -------- pass A: gather once, y1 in registers, y1 stats --------
  half4v y1r[EPT];
  {
    float acc[8] = {0, 0, 0, 0, 0, 0, 0, 0};
    #pragma unroll
    for (int k = 0; k < EPT; ++k) {
      int i = tid + k * S;
      if (i < p.E) {
        half4v ua = p.a16[p.edst[i]];
        half4v ub = p.b16[p.esrc[i]];
        half4v q;
        #pragma unroll
        for (int j = 0; j < 4; ++j) {
          q.v[j] = (_Float16)((float)ua.v[j] + (float)ub.v[j]);
          float yq = (float)q.v[j];
          acc[j] += yq; acc[4 + j] += yq * yq;
        }
        y1r[k] = q;
      }
    }
    for (int i = CAP + tid; i < p.E; i += S) {    // dead at these sizes
      half4v ua = p.a16[p.edst[i]];
      half4v ub = p.b16[p.esrc[i]];
      #pragma unroll
      for (int j = 0; j < 4; ++j) {
        float yq = (float)(_Float16)((float)ua.v[j] + (float)ub.v[j]);
        acc[j] += yq; acc[4 + j] += yq * yq;
      }
    }
    block_reduce_add8(acc, p.stats + 0);
  }
  grid.sync();

  float w2[4][4], bb2[4];
  load_w44(p.msgW2, w2);
  #pragma unroll
  for (int j = 0; j < 4; ++j) bb2[j] = p.msgb2[j];
  float sc1[4], sh1[4];
  finalize_bn_block(p.stats + 0, p.msgg1, p.msgbe1, p.invE, sc1, sh1);

  // -------- pass B: y2 stats from register y1 --------
  {
    float acc[8] = {0, 0, 0, 0, 0, 0, 0, 0};
    #pragma unroll
    for (int k = 0; k < EPT; ++k) {
      int i = tid + k * S;
      if (i < p.E) {
        float r[4], y2[4];
        #pragma unroll
        for (int j = 0; j < 4; ++j) r[j] = fmaxf(0.f, fmaf((float)y1r[k].v[j], sc1[j], sh1[j]));
        layer2(r, w2, bb2, y2);
        #pragma unroll
        for (int j = 0; j < 4; ++j) { acc[j] += y2[j]; acc[4 + j] += y2[j] * y2[j]; }
      }
    }
    for (int i = CAP + tid; i < p.E; i += S) {
      half4v ua = p.a16[p.edst[i]];
      half4v ub = p.b16[p.esrc[i]];
      half4v q;
      #pragma unroll
      for (int j = 0; j < 4; ++j) q.v[j] = (_Float16)((float)ua.v[j] + (float)ub.v[j]);
      float r[4], y2[4];
      #pragma unroll
      for (int j = 0; j < 4; ++j) r[j] = fmaxf(0.f, fmaf((float)q.v[j], sc1[j], sh1[j]));
      layer2(r, w2, bb2, y2);
      #pragma unroll
      for (int j = 0; j < 4; ++j) { acc[j] += y2[j]; acc[4 + j] += y2[j] * y2[j]; }
    }
    block_reduce_add8(acc, p.stats + 8);
  }
  grid.sync();

  float sc2[4], sh2[4];
  finalize_bn_block(p.stats + 8, p.msgg2, p.msgbe2, p.invE, sc2, sh2);

  // -------- pass C: messages -> XCD-local (workgroup-scope) L2 atomics --------
  {
    #pragma unroll
    for (int k = 0; k < EPT; ++k) {
      int i = tid + k * S;
      if (i < p.E) {
        int d = p.edst[i];
        unsigned long long pk = pack_msg(y1r[k], sc1, sh1, w2, bb2, sc2, sh2);
        __hip_atomic_fetch_add(&myCopy[d], pk, __ATOMIC_RELAXED, __HIP_MEMORY_SCOPE_WORKGROUP);
      }
    }
    for (int i = CAP + tid; i < p.E; i += S) {
      half4v ua = p.a16[p.edst[i]];
      half4v ub = p.b16[p.esrc[i]];
      half4v q;
      #pragma unroll
      for (int j = 0; j < 4; ++j) q.v[j] = (_Float16)((float)ua.v[j] + (float)ub.v[j]);
      unsigned long long pk = pack_msg(q, sc1, sh1, w2, bb2, sc2, sh2);
      __hip_atomic_fetch_add(&myCopy[p.edst[i]], pk, __ATOMIC_RELAXED, __HIP_MEMORY_SCOPE_WORKGROUP);
    }
  }
  grid.sync();

  // -------- merge: same-XCD blocks drain their copy into final (far atomics) ----
  {
    const unsigned nChunk = (unsigned)((p.N + TPB - 1) / TPB);
    __shared__ unsigned chunk_sm;
    while (true) {
      __syncthreads();
      if (threadIdx.x == 0)
        chunk_sm = __hip_atomic_fetch_add(&p.ctr[xcd], 1u, __ATOMIC_RELAXED,
                                          __HIP_MEMORY_SCOPE_AGENT);
      __syncthreads();
      unsigned c = chunk_sm;
      if (c >= nChunk) break;
      int idx = (int)c * TPB + threadIdx.x;
      if (idx < p.N) {
        unsigned long long v = myCopy[idx];    // same-L2 dirty line: plain load ok
        if (v) atomicAdd(&p.aggrF[idx], v);    // memory-side final accumulate
      }
    }
  }
  grid.sync();

  // -------- node phase --------
  float uw1[8][4], ub1[4];
  #pragma unroll
  for (int k = 0; k < 8; ++k)
    #pragma unroll
    for (int j = 0; j < 4; ++j) uw1[k][j] = p.updW1[k * 4 + j];
  #pragma unroll
  for (int j = 0; j < 4; ++j) ub1[j] = p.updb1[j];

  float ny[4];
  const bool hasNode = (tid < p.N);
  {
    float acc[8] = {0, 0, 0, 0, 0, 0, 0, 0};
    if (hasNode) {
      float2 pp = ((const float2*)p.pos)[tid];
      float2 vv = ((const float2*)p.vel)[tid];
      unsigned long long pk = __hip_atomic_load(&p.aggrF[tid], __ATOMIC_RELAXED,
                                                __HIP_MEMORY_SCOPE_AGENT);  // bypass stale L2
      float4 ag = unpack_aggr(pk);
      #pragma unroll
      for (int j = 0; j < 4; ++j) {
        float t = ub1[j];
        t = fmaf(pp.x, uw1[0][j], t); t = fmaf(pp.y, uw1[1][j], t);
        t = fmaf(vv.x, uw1[2][j], t); t = fmaf(vv.y, uw1[3][j], t);
        t = fmaf(ag.x, uw1[4][j], t); t = fmaf(ag.y, uw1[5][j], t);
        t = fmaf(ag.z, uw1[6][j], t); t = fmaf(ag.w, uw1[7][j], t);
        ny[j] = t;
        acc[j] += t; acc[4 + j] += t * t;
      }
    }
    block_reduce_add8(acc, p.stats + 16);
  }
  grid.sync();

  float nw2[4][4], nb2[4];
  load_w44(p.updW2, nw2);
  #pragma unroll
  for (int j = 0; j < 4; ++j) nb2[j] = p.updb2[j];
  float nsc1[4], nsh1[4];
  finalize_bn_block(p.stats + 16, p.updg1, p.updbe1, p.invN, nsc1, nsh1);

  float ny2[4];
  {
    float acc[8] = {0, 0, 0, 0, 0, 0, 0, 0};
    if (hasNode) {
      float r[4];
      #pragma unroll
      for (int j = 0; j < 4; ++j) r[j] = fmaxf(0.f, fmaf(ny[j], nsc1[j], nsh1[j]));
      layer2(r, nw2, nb2, ny2);
      #pragma unroll
      for (int j = 0; j < 4; ++j) { acc[j] += ny2[j]; acc[4 + j] += ny2[j] * ny2[j]; }
    }
    block_reduce_add8(acc, p.stats + 24);
  }
  grid.sync();

  float nsc2[4], nsh2[4];
  finalize_bn_block(p.stats + 24, p.updg2, p.updbe2, p.invN, nsc2, nsh2);

  if (hasNode) {
    float u[4];
    #pragma unroll
    for (int j = 0; j < 4; ++j) u[j] = fmaxf(0.f, fmaf(ny2[j], nsc2[j], nsh2[j]));
    float o0 = p.predb[0], o1 = p.predb[1];
    #pragma unroll
    for (int k = 0; k < 4; ++k) {
      o0 = fmaf(u[k], p.predW[2 * k], o0);
      o1 = fmaf(u[k], p.predW[2 * k + 1], o1);
    }
    p.out[tid] = make_float2(o0, o1);
  }
}

// ======================= fallback path (no coop) ==========================
__global__ void finalize_bn_k(const double* __restrict__ stats, const float* __restrict__ g,
                              const float* __restrict__ be, float* __restrict__ bn,
                              double invCount) {
  int j = threadIdx.x;
  if (j < 4) {
    float mean = (float)(stats[j] * invCount);
    float ex2  = (float)(stats[4 + j] * invCount);
    float var  = ex2 - mean * mean;
    float sc = g[j] * rsqrtf(var + 1e-5f);
    bn[j] = sc;
    bn[4 + j] = be[j] - mean * sc;
  }
}

__global__ void fb_stats1(const int* __restrict__ esrc, const int* __restrict__ edst,
                          const half4v* __restrict__ a16, const half4v* __restrict__ b16,
                          double* __restrict__ stats, int E) {
  float acc[8] = {0, 0, 0, 0, 0, 0, 0, 0};
  const int gs = gridDim.x * blockDim.x;
  for (int i = blockIdx.x * blockDim.x + threadIdx.x; i < E; i += gs) {
    half4v ua = a16[edst[i]];
    half4v ub = b16[esrc[i]];
    #pragma unroll
    for (int j = 0; j < 4; ++j) {
      float yq = (float)(_Float16)((float)ua.v[j] + (float)ub.v[j]);
      acc[j] += yq; acc[4 + j] += yq * yq;
    }
  }
  block_reduce_add8(acc, stats);
}

__global__ void fb_stats2(const int* __restrict__ esrc, const int* __restrict__ edst,
                          const half4v* __restrict__ a16, const half4v* __restrict__ b16,
                          const float* __restrict__ W2, const float* __restrict__ b2,
                          const float* __restrict__ bn1, double* __restrict__ stats, int E) {
  float w2[4][4], bb2[4], sc1[4], sh1[4];
  load_w44(W2, w2);
  #pragma unroll
  for (int j = 0; j < 4; ++j) { bb2[j] = b2[j]; sc1[j] = bn1[j]; sh1[j] = bn1[4 + j]; }
  float acc[8] = {0, 0, 0, 0, 0, 0, 0, 0};
  const int gs = gridDim.x * blockDim.x;
  for (int i = blockIdx.x * blockDim.x + threadIdx.x; i < E; i += gs) {
    half4v ua = a16[edst[i]];
    half4v ub = b16[esrc[i]];
    float r[4], y2[4];
    #pragma unroll
    for (int j = 0; j < 4; ++j) {
      float yq = (float)(_Float16)((float)ua.v[j] + (float)ub.v[j]);
      r[j] = fmaxf(0.f, fmaf(yq, sc1[j], sh1[j]));
    }
    layer2(r, w2, bb2, y2);
    #pragma unroll
    for (int j = 0; j < 4; ++j) { acc[j] += y2[j]; acc[4 + j] += y2[j] * y2[j]; }
  }
  block_reduce_add8(acc, stats);
}

__global__ void fb_scatter(const int* __restrict__ esrc, const int* __restrict__ edst,
                           const half4v* __restrict__ a16, const half4v* __restrict__ b16,
                           const float* __restrict__ W2, const float* __restrict__ b2,
                           const float* __restrict__ bn1, const float* __restrict__ bn2,
                           unsigned long long* __restrict__ aggrF, int E) {
  float w2[4][4], bb2[4], sc1[4], sh1[4], sc2[4], sh2[4];
  load_w44(W2, w2);
  #pragma unroll
  for (int j = 0; j < 4; ++j) {
    bb2[j] = b2[j];
    sc1[j] = bn1[j]; sh1[j] = bn1[4 + j];
    sc2[j] = bn2[j]; sh2[j] = bn2[4 + j];
  }
  const int gs = gridDim.x * blockDim.x;
  for (int i = blockIdx.x * blockDim.x + threadIdx.x; i < E; i += gs) {
    half4v ua = a16[edst[i]];
    half4v ub = b16[esrc[i]];
    half4v q;
    #pragma unroll
    for (int j = 0; j < 4; ++j) q.v[j] = (_Float16)((float)ua.v[j] + (float)ub.v[j]);
    unsigned long long pk = pack_msg(q, sc1, sh1, w2, bb2, sc2, sh2);
    atomicAdd(&aggrF[edst[i]], pk);
  }
}

__global__ void fb_nstats1(const float* __restrict__ pos, const float* __restrict__ vel,
                           const unsigned long long* __restrict__ aggrF,
                           const float* __restrict__ W1, const float* __restrict__ b1,
                           double* __restrict__ stats, int n) {
  float w[8][4], bb[4];
  #pragma unroll
  for (int k = 0; k < 8; ++k)
    #pragma unroll
    for (int j = 0; j < 4; ++j) w[k][j] = W1[k * 4 + j];
  #pragma unroll
  for (int j = 0; j < 4; ++j) bb[j] = b1[j];
  float acc[8] = {0, 0, 0, 0, 0, 0, 0, 0};
  const int gs = gridDim.x * blockDim.x;
  for (int i = blockIdx.x * blockDim.x + threadIdx.x; i < n; i += gs) {
    float2 pp = ((const float2*)pos)[i];
    float2 vv = ((const float2*)vel)[i];
    float4 ag = unpack_aggr(aggrF[i]);
    #pragma unroll
    for (int j = 0; j < 4; ++j) {
      float t = bb[j];
      t = fmaf(pp.x, w[0][j], t); t = fmaf(pp.y, w[1][j], t);
      t = fmaf(vv.x, w[2][j], t); t = fmaf(vv.y, w[3][j], t);
      t = fmaf(ag.x, w[4][j], t); t = fmaf(ag.y, w[5][j], t);
      t = fmaf(ag.z, w[6][j], t); t = fmaf(ag.w, w[7][j], t);
      acc[j] += t; acc[4 + j] += t * t;
    }
  }
  block_reduce_add8(acc, stats);
}

__global__ void fb_nstats2(const float* __restrict__ pos, const float* __restrict__ vel,
                           const unsigned long long* __restrict__ aggrF,
                           const float* __restrict__ W1, const float* __restrict__ b1,
                           const float* __restrict__ W2, const float* __restrict__ b2,
                           const float* __restrict__ bn1, double* __restrict__ stats, int n) {
  float w[8][4], bb[4], w2[4][4], bb2[4], sc1[4], sh1[4];
  #pragma unroll
  for (int k = 0; k < 8; ++k)
    #pragma unroll
    for (int j = 0; j < 4; ++j) w[k][j] = W1[k * 4 + j];
  load_w44(W2, w2);
  #pragma unroll
  for (int j = 0; j < 4; ++j) { bb[j] = b1[j]; bb2[j] = b2[j]; sc1[j] = bn1[j]; sh1[j] = bn1[4 + j]; }
  float acc[8] = {0, 0, 0, 0, 0, 0, 0, 0};
  const int gs = gridDim.x * blockDim.x;
  for (int i = blockIdx.x * blockDim.x + threadIdx.x; i < n; i += gs) {
    float2 pp = ((const float2*)pos)[i];
    float2 vv = ((const float2*)vel)[i];
    float4 ag = unpack_aggr(aggrF[i]);
    float y[4], r[4], y2[4];
    #pragma unroll
    for (int j = 0; j < 4; ++j) {
      float t = bb[j];
      t = fmaf(pp.x, w[0][j], t); t = fmaf(pp.y, w[1][j], t);
      t = fmaf(vv.x, w[2][j], t); t = fmaf(vv.y, w[3][j], t);
      t = fmaf(ag.x, w[4][j], t); t = fmaf(ag.y, w[5][j], t);
      t = fmaf(ag.z, w[6][j], t); t = fmaf(ag.w, w[7][j], t);
      y[j] = t;
    }
    #pragma unroll
    for (int j = 0; j < 4; ++j) r[j] = fmaxf(0.f, fmaf(y[j], sc1[j], sh1[j]));
    layer2(r, w2, bb2, y2);
    #pragma unroll
    for (int j = 0; j < 4; ++j) { acc[j] += y2[j]; acc[4 + j] += y2[j] * y2[j]; }
  }
  block_reduce_add8(acc, stats);
}

__global__ void fb_nout(const float* __restrict__ pos, const float* __restrict__ vel,
                        const unsigned long long* __restrict__ aggrF,
                        const float* __restrict__ W1, const float* __restrict__ b1,
                        const float* __restrict__ W2, const float* __restrict__ b2,
                        const float* __restrict__ bn1, const float* __restrict__ bn2,
                        const float* __restrict__ pW, const float* __restrict__ pb,
                        float2* __restrict__ out, int n) {
  float w[8][4], bb[4], w2[4][4], bb2[4], sc1[4], sh1[4], sc2[4], sh2[4];
  #pragma unroll
  for (int k = 0; k < 8; ++k)
    #pragma unroll
    for (int j = 0; j < 4; ++j) w[k][j] = W1[k * 4 + j];
  load_w44(W2, w2);
  #pragma unroll
  for (int j = 0; j < 4; ++j) {
    bb[j] = b1[j]; bb2[j] = b2[j];
    sc1[j] = bn1[j]; sh1[j] = bn1[4 + j];
    sc2[j] = bn2[j]; sh2[j] = bn2[4 + j];
  }
  int i = blockIdx.x * blockDim.x + threadIdx.x;
  if (i < n) {
    float2 pp = ((const float2*)pos)[i];
    float2 vv = ((const float2*)vel)[i];
    float4 ag = unpack_aggr(aggrF[i]);
    float y[4], r[4], y2[4], u[4];
    #pragma unroll
    for (int j = 0; j < 4; ++j) {
      float t = bb[j];
      t = fmaf(pp.x, w[0][j], t); t = fmaf(pp.y, w[1][j], t);
      t = fmaf(vv.x, w[2][j], t); t = fmaf(vv.y, w[3][j], t);
      t = fmaf(ag.x, w[4][j], t); t = fmaf(ag.y, w[5][j], t);
      t = fmaf(ag.z, w[6][j], t); t = fmaf(ag.w, w[7][j], t);
      y[j] = t;
    }
    #pragma unroll
    for (int j = 0; j < 4; ++j) r[j] = fmaxf(0.f, fmaf(y[j], sc1[j], sh1[j]));
    layer2(r, w2, bb2, y2);
    #pragma unroll
    for (int j = 0; j < 4; ++j) u[j] = fmaxf(0.f, fmaf(y2[j], sc2[j], sh2[j]));
    float o0 = pb[0], o1 = pb[1];
    #pragma unroll
    for (int k = 0; k < 4; ++k) { o0 = fmaf(u[k], pW[2 * k], o0); o1 = fmaf(u[k], pW[2 * k + 1], o1); }
    out[i] = make_float2(o0, o1);
  }
}

extern "C" void kernel_launch(void* const* d_in, const int* in_sizes, int n_in,
                              void* d_out, int out_size, void* d_ws, size_t ws_size,
                              hipStream_t stream) {
  const float* pos = (const float*)d_in[0];
  const float* vel = (const float*)d_in[1];
  const int* eidx  = (const int*)d_in[2];

  const int N = in_sizes[0] / 2;       // pos is (N,2)
  const int E = in_sizes[2] / 2;       // edge_index is (2,E)
  const int* esrc = eidx;
  const int* edst = eidx + E;

  // ws: [aggrF N*8][copies 8N*8][stats 256B][bnp 128B][ctr 32B] (zeroed) | [a16 N*8][b16 N*8]
  char* ws = (char*)d_ws;
  size_t off = 0;
  unsigned long long* aggrF  = (unsigned long long*)(ws + off); off += (size_t)N * 8;
  unsigned long long* copies = (unsigned long long*)(ws + off); off += (size_t)N * 8 * 8;
  double* stats = (double*)(ws + off); off += 32 * sizeof(double);
  float* bnp = (float*)(ws + off); off += 32 * sizeof(float);
  unsigned* ctr = (unsigned*)(ws + off); off += 8 * sizeof(unsigned);
  const size_t zeroBytes = off;
  half4v* a16 = (half4v*)(ws + off); off += (size_t)N * 8;
  half4v* b16 = (half4v*)(ws + off); off += (size_t)N * 8;

  hipMemsetAsync(ws, 0, zeroBytes, stream);

  const int nodeBlocks = (N + TPB - 1) / TPB;
  node_prep<<<nodeBlocks, TPB, 0, stream>>>(
      pos, vel, (const float*)d_in[3], (const float*)d_in[4], a16, b16, N);

  Params prm;
  prm.esrc = esrc; prm.edst = edst;
  prm.pos = pos; prm.vel = vel;
  prm.msgW2 = (const float*)d_in[7];  prm.msgb2 = (const float*)d_in[8];
  prm.msgg1 = (const float*)d_in[5];  prm.msgbe1 = (const float*)d_in[6];
  prm.msgg2 = (const float*)d_in[9];  prm.msgbe2 = (const float*)d_in[10];
  prm.updW1 = (const float*)d_in[11]; prm.updb1 = (const float*)d_in[12];
  prm.updg1 = (const float*)d_in[13]; prm.updbe1 = (const float*)d_in[14];
  prm.updW2 = (const float*)d_in[15]; prm.updb2 = (const float*)d_in[16];
  prm.updg2 = (const float*)d_in[17]; prm.updbe2 = (const float*)d_in[18];
  prm.predW = (const float*)d_in[19]; prm.predb = (const float*)d_in[20];
  prm.a16 = a16; prm.b16 = b16;
  prm.aggrF = aggrF; prm.copies = copies; prm.stats = stats; prm.ctr = ctr;
  prm.out = (float2*)d_out;
  prm.N = N; prm.E = E;
  prm.invE = 1.0 / (double)E; prm.invN = 1.0 / (double)N;

  void* args[] = { &prm };
  hipError_t e = hipLaunchCooperativeKernel((const void*)mega, dim3(CGRID), dim3(TPB),
                                            args, 0, stream);
  if (e != hipSuccess) {
    // deterministic fallback: proven multi-kernel sequence (far atomics)
    const int edgeBlocks = 2048;
    fb_stats1<<<edgeBlocks, TPB, 0, stream>>>(esrc, edst, a16, b16, stats, E);
    finalize_bn_k<<<1, 64, 0, stream>>>(stats, (const float*)d_in[5], (const float*)d_in[6],
                                        bnp, 1.0 / (double)E);
    fb_stats2<<<edgeBlocks, TPB, 0, stream>>>(esrc, edst, a16, b16,
                                              (const float*)d_in[7], (const float*)d_in[8],
                                              bnp, stats + 8, E);
    finalize_bn_k<<<1, 64, 0, stream>>>(stats + 8, (const float*)d_in[9], (const float*)d_in[10],
                                        bnp + 8, 1.0 / (double)E);
    fb_scatter<<<edgeBlocks, TPB, 0, stream>>>(esrc, edst, a16, b16,
                                               (const float*)d_in[7], (const float*)d_in[8],
                                               bnp, bnp + 8, aggrF, E);
    fb_nstats1<<<nodeBlocks, TPB, 0, stream>>>(pos, vel, aggrF,
                                               (const float*)d_in[11], (const float*)d_in[12],
                                               stats + 16, N);
    finalize_bn_k<<<1, 64, 0, stream>>>(stats + 16, (const float*)d_in[13], (const float*)d_in[14],
                                        bnp + 16, 1.0 / (double)N);
    fb_nstats2<<<nodeBlocks, TPB, 0, stream>>>(pos, vel, aggrF,
                                               (const float*)d_in[11], (const float*)d_in[12],
                                               (const float*)d_in[15], (const float*)d_in[16],
                                               bnp + 16, stats + 24, N);
    finalize_bn_k<<<1, 64, 0, stream>>>(stats + 24, (const float*)d_in[17], (const float*)d_in[18],
                                        bnp + 24, 1.0 / (double)N);
    fb_nout<<<nodeBlocks, TPB, 0, stream>>>(pos, vel, aggrF,
                                            (const float*)d_in[11], (const float*)d_in[12],
                                            (const float*)d_in[15], (const float*)d_in[16],
                                            bnp + 16, bnp + 24,
                                            (const float*)d_in[19], (const float*)d_in[20],
                                            (float2*)d_out, N);
  }
}